// Round 1
// baseline (359.023 us; speedup 1.0000x reference)
//
#include <hip/hip_runtime.h>

// Simple_Cross2: x[16384,512] -> cross -> 2048 -> 2048 -> 1024 -> 512 -> 1
// bf16 MFMA (16x16x32) GEMMs, fp32 accumulate, fused bias+relu.
// R2: BK=64 + XOR swizzle -> 0 bank conflicts.
// R3: 64x128 wave tile, block 128x256, bm-fast grid -> G2 119us.
// R4 FAILED: dbuf prefetch (__syncthreads drains vmcnt(0) incl. prefetch).
// R5 FAILED: 32x32x16 shape. R6/R7: head fusion + bm-fast grid. 345.5us.
// R8: port G1/G2/G3 to the 8-phase 256x256 schedule (T3+T4+T5):
//     raw s_barrier + counted s_waitcnt vmcnt(6) keeps 3 half-tiles of
//     global_load_lds in flight across barriers (never drains to 0 in the
//     main loop -- exactly what R4 could not do through __syncthreads).
//     8 waves (2M x 4N), per-wave 128x64 output via interleaved row/col
//     blocks (64*wr & 128+64*wr rows; 32*wc & 128+32*wc cols) so each LDS
//     half-tile region dies at a distinct phase -> one half-tile staged per
//     phase into a dead region. vmcnt(6) at ph4/ph8. LDS 128 KiB, 1 blk/CU.

#define BK 64

typedef __bf16 bf16x8 __attribute__((ext_vector_type(8)));
typedef float  f32x4  __attribute__((ext_vector_type(4)));
typedef unsigned short u16x4 __attribute__((ext_vector_type(4)));

__device__ __forceinline__ unsigned short f2bf(float f) {
    unsigned int u = __builtin_bit_cast(unsigned int, f);
    u += 0x7fffu + ((u >> 16) & 1u);          // round-to-nearest-even
    return (unsigned short)(u >> 16);
}

__device__ __forceinline__ void async16(const void* g, void* l) {
    __builtin_amdgcn_global_load_lds(
        (const __attribute__((address_space(1))) unsigned int*)g,
        (__attribute__((address_space(3))) unsigned int*)l,
        16, 0, 0);
}

#define BAR()   __builtin_amdgcn_s_barrier()
#define LGKM0() asm volatile("s_waitcnt lgkmcnt(0)" ::: "memory")
#define VMW(n)  asm volatile("s_waitcnt vmcnt(" #n ")" ::: "memory")

// read 4 A rowfrags x 2 k-halves (8 x ds_read_b128)
#define RDA(REGION) do { _Pragma("unroll") \
    for (int f = 0; f < 4; ++f) { \
        af[f][0] = *(const bf16x8*)(lds + (REGION) + aRd + f * 1024 + c0); \
        af[f][1] = *(const bf16x8*)(lds + (REGION) + aRd + f * 1024 + c1); } } while (0)

// read 2 B colfrags x 2 k-halves (4 x ds_read_b128)
#define RDB(DST, REGION) do { _Pragma("unroll") \
    for (int c = 0; c < 2; ++c) { \
        DST[c][0] = *(const bf16x8*)(lds + (REGION) + bRd + c * 1024 + c0); \
        DST[c][1] = *(const bf16x8*)(lds + (REGION) + bRd + c * 1024 + c1); } } while (0)

// 16 MFMA cluster (4 rowfrag x 2 colfrag x 2 k-halves), setprio-wrapped (T5)
#define MM16(HA, HB, AF, BF) do { \
    __builtin_amdgcn_s_setprio(1); \
    _Pragma("unroll") for (int f = 0; f < 4; ++f) \
    _Pragma("unroll") for (int c = 0; c < 2; ++c) { \
        acc[HA][f][HB][c] = __builtin_amdgcn_mfma_f32_16x16x32_bf16( \
            AF[f][0], BF[c][0], acc[HA][f][HB][c], 0, 0, 0); \
        acc[HA][f][HB][c] = __builtin_amdgcn_mfma_f32_16x16x32_bf16( \
            AF[f][1], BF[c][1], acc[HA][f][HB][c], 0, 0, 0); } \
    __builtin_amdgcn_s_setprio(0); } while (0)

// ---------------------------------------------------------------------------
// 8-phase 256x256 tile, BK=64, 512 threads. C = relu(A[M,K] * B[N,K]^T + b).
// LDS elem(row,c) at row*64 + (((c>>3) ^ (row&7))*8 + (c&7)) per 128x64 half.
// ---------------------------------------------------------------------------
__global__ __launch_bounds__(512, 2)
void gemm8_bt_bias_relu(const unsigned short* __restrict__ A,
                        const unsigned short* __restrict__ B,
                        const float* __restrict__ bias,
                        unsigned short* __restrict__ C,
                        int M, int N, int K)
{
    __shared__ __align__(16) unsigned short L[65536];   // 128 KiB
    unsigned short* lds = L;

    // regions (element offsets): A buf b half h = b*16384 + h*8192; B = +32768
    constexpr int RA00 = 0,     RA01 = 8192,  RA10 = 16384, RA11 = 24576;
    constexpr int RB00 = 32768, RB01 = 40960, RB10 = 49152, RB11 = 57344;

    const int tid  = threadIdx.x;
    const int lane = tid & 63;
    const int wave = tid >> 6;
    const int quad = lane >> 4;
    const int l16  = lane & 15;
    const int wr   = wave >> 2;          // 0..1
    const int wc   = wave & 3;           // 0..3

    const int bm = blockIdx.x * 256;
    const int bn = blockIdx.y * 256;

    // ---- staging addressing (pre-swizzled global source, linear LDS dest)
    const int lrow = tid >> 3;                       // 0..63
    const int cswz = ((tid & 7) ^ (lrow & 7)) * 8;
    const int tid8 = tid * 8;
    const size_t rstep64 = (size_t)64 * K;
    const unsigned short* gaL = A + (size_t)(bm + lrow) * K + cswz;
    const unsigned short* gaH = gaL + (size_t)128 * K;
    const unsigned short* gbL = B + (size_t)(bn + lrow) * K + cswz;
    const unsigned short* gbH = gbL + (size_t)128 * K;

    auto stage = [&](const unsigned short* g, int region, int ko) {
        async16(g + ko,           lds + region + tid8);
        async16(g + rstep64 + ko, lds + region + 4096 + tid8);
    };

    // ---- fragment read addressing (R3-proven swizzle algebra)
    const int xa = l16 & 7;
    const int c0 = (quad ^ xa) * 8;                  // k-half 0
    const int c1 = ((quad ^ 4) ^ xa) * 8;            // k-half 1
    const int aRd = (64 * wr + l16) * BK;            // + f*1024 + region
    const int bRd = (32 * wc + l16) * BK;            // + c*1024 + region

    f32x4 acc[2][4][2][2] = {};                      // [rowhalf][f][colhalf][c]
    bf16x8 af[4][2], bfl[2][2], bfh[2][2];

    // ---- prologue: tile0 all 4 halves -> buf0; tile1 A0,B0,B1 -> buf1
    stage(gaL, RA00, 0);
    stage(gbL, RB00, 0);
    stage(gbH, RB01, 0);
    stage(gaH, RA01, 0);
    stage(gaL, RA10, 64);
    stage(gbL, RB10, 64);
    stage(gbH, RB11, 64);
    VMW(6);                  // tile0 landed; tile1's 3 halves in flight
    BAR();

    const int nIter = K >> 7;                        // 2 K-tiles per iter
    for (int i = 0; i < nIter; ++i) {
        const int k1 = (2 * i + 1) << 6;             // never exceeds K-64
        int k2 = (2 * i + 2) << 6; if (k2 >= K) k2 -= K;   // tail wrap
        int k3 = (2 * i + 3) << 6; if (k3 >= K) k3 -= K;

        // ph1: tile t: Alow x Blow (buf0). stage A1(t+1)->RA11 (dead ph7')
        RDA(RA00); RDB(bfl, RB00);
        stage(gaH, RA11, k1);
        BAR(); LGKM0();
        MM16(0, 0, af, bfl);
        BAR();

        // ph2: Alow x Bhigh. stage A0(t+2)->RA00 (dead ph1)
        RDB(bfh, RB01);
        stage(gaL, RA00, k2);
        BAR(); LGKM0();
        MM16(0, 1, af, bfh);
        BAR();

        // ph3: Ahigh x Bhigh. stage B0(t+2)->RB00 (dead ph1)
        RDA(RA01);
        stage(gbL, RB00, k2);
        BAR(); LGKM0();
        MM16(1, 1, af, bfh);
        BAR();

        // ph4: Ahigh x Blow (regs). stage B1(t+2)->RB01 (dead ph2)
        stage(gbH, RB01, k2);
        BAR();
        MM16(1, 0, af, bfl);
        VMW(6);              // tile t+1 fully landed; t+2's 3 halves in flight
        BAR();

        // ph5: tile t+1: Alow x Blow (buf1). stage A1(t+2)->RA01 (dead ph3)
        RDA(RA10); RDB(bfl, RB10);
        stage(gaH, RA01, k2);
        BAR(); LGKM0();
        MM16(0, 0, af, bfl);
        BAR();

        // ph6: Alow x Bhigh. stage A0(t+3)->RA10 (dead ph5)
        RDB(bfh, RB11);
        stage(gaL, RA10, k3);
        BAR(); LGKM0();
        MM16(0, 1, af, bfh);
        BAR();

        // ph7: Ahigh x Bhigh. stage B0(t+3)->RB10 (dead ph5)
        RDA(RA11);
        stage(gbL, RB10, k3);
        BAR(); LGKM0();
        MM16(1, 1, af, bfh);
        BAR();

        // ph8: Ahigh x Blow. stage B1(t+3)->RB11 (dead ph6)
        stage(gbH, RB11, k3);
        BAR();
        MM16(1, 0, af, bfl);
        VMW(6);              // tile t+2 fully landed; t+3's 3 halves in flight
        BAR();
    }
    VMW(0);                  // drain wrapped stages before LDS dealloc

    // ---- epilogue: bias + relu + bf16 store (R3 index algebra)
    float bv[2][2];
#pragma unroll
    for (int hb = 0; hb < 2; ++hb)
#pragma unroll
        for (int c = 0; c < 2; ++c)
            bv[hb][c] = bias[bn + hb * 128 + wc * 32 + c * 16 + l16];

#pragma unroll
    for (int ha = 0; ha < 2; ++ha)
#pragma unroll
    for (int f = 0; f < 4; ++f) {
        const int row0 = bm + ha * 128 + wr * 64 + f * 16 + quad * 4;
#pragma unroll
        for (int hb = 0; hb < 2; ++hb)
#pragma unroll
        for (int c = 0; c < 2; ++c) {
            const int col = bn + hb * 128 + wc * 32 + c * 16 + l16;
#pragma unroll
            for (int r = 0; r < 4; ++r) {
                float v = fmaxf(acc[ha][f][hb][c][r] + bv[hb][c], 0.0f);
                C[(size_t)(row0 + r) * N + col] = f2bf(v);
            }
        }
    }
}

// ---------------------------------------------------------------------------
// G4 + head fused: h4 = relu(A @ W4^T + b4) is NOT stored; each block
// computes partial dot(h4_row, Wo_cols) and atomicAdds into out[row].
// out pre-initialized to bo in prep_kernel. Block tile 128x128, acc[4][4].
// (unchanged from R7 -- ~20us, low-risk)
// ---------------------------------------------------------------------------
__global__ __launch_bounds__(256, 2)
void gemm_bt_head(const unsigned short* __restrict__ A,
                  const unsigned short* __restrict__ B,
                  const float* __restrict__ bias,
                  const float* __restrict__ Wo,
                  float* __restrict__ out,
                  int M, int N, int K)
{
    constexpr int BN = 128;
    constexpr int JT = 4;
    __shared__ __align__(16) unsigned short As[128 * BK];
    __shared__ __align__(16) unsigned short Bs[BN * BK];

    const int tid  = threadIdx.x;
    const int lane = tid & 63;
    const int wave = tid >> 6;
    const int quad = lane >> 4;
    const int l16  = lane & 15;

    const int bm = blockIdx.x * 128;
    const int bn = blockIdx.y * BN;
    const int wm = (wave & 1) * 64;
    const int wn = (wave >> 1) * 64;

    const int lrow = tid >> 3;
    const int gcol = ((tid & 7) ^ (lrow & 7)) * 8;

    const unsigned short* gaBase = A + (size_t)(bm + lrow) * K + gcol;
    const unsigned short* gbBase = B + (size_t)(bn + lrow) * K + gcol;

    unsigned short* lA = As + tid * 8;
    unsigned short* lB = Bs + tid * 8;

    const int xa = l16 & 7;
    const unsigned short* As_w = As + (wm + l16) * BK;
    const unsigned short* Bs_w = Bs + (wn + l16) * BK;
    const int c0 = (quad ^ xa) * 8;
    const int c1 = ((quad ^ 4) ^ xa) * 8;

    f32x4 acc[4][JT] = {};

    for (int k0 = 0; k0 < K; k0 += BK) {
#pragma unroll
        for (int i = 0; i < 4; ++i)
            async16(gaBase + (size_t)(i * 32) * K + k0, lA + i * 2048);
#pragma unroll
        for (int i = 0; i < JT; ++i)
            async16(gbBase + (size_t)(i * 32) * K + k0, lB + i * 2048);
        __syncthreads();

#pragma unroll
        for (int kk = 0; kk < 2; ++kk) {
            const int cs = kk ? c1 : c0;
            bf16x8 af[4], bfr[JT];
#pragma unroll
            for (int i = 0; i < 4; ++i)  af[i]  = *(const bf16x8*)(As_w + i * 16 * BK + cs);
#pragma unroll
            for (int j = 0; j < JT; ++j) bfr[j] = *(const bf16x8*)(Bs_w + j * 16 * BK + cs);
#pragma unroll
            for (int i = 0; i < 4; ++i)
#pragma unroll
                for (int j = 0; j < JT; ++j)
                    acc[i][j] = __builtin_amdgcn_mfma_f32_16x16x32_bf16(
                        af[i], bfr[j], acc[i][j], 0, 0, 0);
        }
        __syncthreads();
    }

    float bv[JT], wov[JT];
#pragma unroll
    for (int j = 0; j < JT; ++j) {
        const int col = bn + wn + j * 16 + l16;
        bv[j]  = bias[col];
        wov[j] = Wo[col];
    }

#pragma unroll
    for (int i = 0; i < 4; ++i) {
#pragma unroll
        for (int r = 0; r < 4; ++r) {
            float ws = 0.f;
#pragma unroll
            for (int j = 0; j < JT; ++j) {
                float v = acc[i][j][r] + bv[j];
                v = fmaxf(v, 0.0f);
                ws += v * wov[j];
            }
#pragma unroll
            for (int off = 8; off > 0; off >>= 1)
                ws += __shfl_xor(ws, off, 64);
            if (l16 == 0) {
                const int row = bm + wm + i * 16 + quad * 4 + r;
                atomicAdd(&out[row], ws);
            }
        }
    }
}

// ---------------------------------------------------------------------------
// Merged prep: [0,7680) convert W1..W4 fp32->bf16; [7680,11776) cross layer;
// [11776,11840) init out[m] = bo.   (unchanged from R7)
// ---------------------------------------------------------------------------
__global__ __launch_bounds__(256)
void prep_kernel(const float* __restrict__ x, const float* __restrict__ cw,
                 const float* __restrict__ cb, unsigned short* __restrict__ h0,
                 const float* __restrict__ s1, const float* __restrict__ s2,
                 const float* __restrict__ s3, const float* __restrict__ s4,
                 unsigned short* __restrict__ d1, unsigned short* __restrict__ d2,
                 unsigned short* __restrict__ d3, unsigned short* __restrict__ d4,
                 const float* __restrict__ bo, float* __restrict__ out)
{
    const int b = blockIdx.x;
    if (b < 7680) {
        long t = (long)b * 256 + threadIdx.x;
        const float* s; unsigned short* d; long off;
        if (t < 262144L)       { s = s1; d = d1; off = t; }
        else if (t < 1310720L) { s = s2; d = d2; off = t - 262144L; }
        else if (t < 1835008L) { s = s3; d = d3; off = t - 1310720L; }
        else                   { s = s4; d = d4; off = t - 1835008L; }
        f32x4 f = *(const f32x4*)(s + off * 4);
        u16x4 o;
#pragma unroll
        for (int i = 0; i < 4; ++i) o[i] = f2bf(f[i]);
        *(u16x4*)(d + off * 4) = o;
    } else if (b < 11776) {
        const int row  = (b - 7680) * 4 + (threadIdx.x >> 6);
        const int lane = threadIdx.x & 63;
        const float* xr = x + (size_t)row * 512;
        float xv[8];
        float s = 0.f;
#pragma unroll
        for (int i = 0; i < 8; ++i) {
            const int c = lane + i * 64;
            xv[i] = xr[c];
            s += xv[i] * cw[c];
        }
#pragma unroll
        for (int off = 32; off > 0; off >>= 1) s += __shfl_down(s, off, 64);
        s = __shfl(s, 0, 64);
        unsigned short* hr = h0 + (size_t)row * 512;
#pragma unroll
        for (int i = 0; i < 8; ++i) {
            const int c = lane + i * 64;
            hr[c] = f2bf(xv[i] * s + cb[c] + xv[i]);
        }
    } else {
        const int t = (b - 11776) * 256 + threadIdx.x;   // 64 blocks = 16384
        out[t] = bo[0];
    }
}

// ---------------------------------------------------------------------------
extern "C" void kernel_launch(void* const* d_in, const int* in_sizes, int n_in,
                              void* d_out, int out_size, void* d_ws, size_t ws_size,
                              hipStream_t stream)
{
    const float* x  = (const float*)d_in[0];
    const float* cw = (const float*)d_in[1];
    const float* cb = (const float*)d_in[2];
    const float* W1 = (const float*)d_in[3];  const float* b1 = (const float*)d_in[4];
    const float* W2 = (const float*)d_in[5];  const float* b2 = (const float*)d_in[6];
    const float* W3 = (const float*)d_in[7];  const float* b3 = (const float*)d_in[8];
    const float* W4 = (const float*)d_in[9];  const float* b4 = (const float*)d_in[10];
    const float* Wo = (const float*)d_in[11]; const float* bo = (const float*)d_in[12];
    float* out = (float*)d_out;

    // workspace carve (~143 MB)
    char* p = (char*)d_ws;
    unsigned short* wb1 = (unsigned short*)p; p += (size_t)2048 * 512  * 2;
    unsigned short* wb2 = (unsigned short*)p; p += (size_t)2048 * 2048 * 2;
    unsigned short* wb3 = (unsigned short*)p; p += (size_t)1024 * 2048 * 2;
    unsigned short* wb4 = (unsigned short*)p; p += (size_t)512  * 1024 * 2;
    unsigned short* actA = (unsigned short*)p; p += (size_t)16384 * 2048 * 2; // h0,h2
    unsigned short* actB = (unsigned short*)p;                                // h1,h3

    prep_kernel<<<11840, 256, 0, stream>>>(x, cw, cb, actA,
                                           W1, W2, W3, W4, wb1, wb2, wb3, wb4,
                                           bo, out);

    // h1 = relu(h0 @ W1^T + b1)   [16384,2048], K=512
    gemm8_bt_bias_relu<<<dim3(64, 8), 512, 0, stream>>>(actA, wb1, b1, actB, 16384, 2048, 512);
    // h2 = relu(h1 @ W2^T + b2)   [16384,2048], K=2048
    gemm8_bt_bias_relu<<<dim3(64, 8), 512, 0, stream>>>(actB, wb2, b2, actA, 16384, 2048, 2048);
    // h3 = relu(h2 @ W3^T + b3)   [16384,1024], K=2048
    gemm8_bt_bias_relu<<<dim3(64, 4), 512, 0, stream>>>(actA, wb3, b3, actB, 16384, 1024, 2048);
    // out += sum_cols relu(h3 @ W4^T + b4) * Wo   [16384,512] fused head
    gemm_bt_head<<<dim3(128, 4), 256, 0, stream>>>(actB, wb4, b4, Wo, out, 16384, 512, 1024);
}

// Round 2
// 344.190 us; speedup vs baseline: 1.0431x; 1.0431x over previous
//
#include <hip/hip_runtime.h>

// Simple_Cross2: x[16384,512] -> cross -> 2048 -> 2048 -> 1024 -> 512 -> 1
// bf16 MFMA (16x16x32) GEMMs, fp32 accumulate, fused bias+relu.
// R2: BK=64 + XOR swizzle -> 0 bank conflicts.
// R3: 64x128 wave tile, block 128x256 2-phase -> G2 119us.
// R8: 8-phase 256x256 counted-vmcnt port -> G2 130us, MfmaUtil 44.7 (< m201's
//     62): each phase paid 2 barriers + unhidden ds_read latency (reads ->
//     BAR -> lgkm0 -> MFMA serializes in lockstep).
// R9: retime same dataflow: ds_reads for phase p+1 issue in phase p's TAIL
//     (overlap MFMA drain + barrier); ONE barrier per phase (H1 still holds:
//     every stage's target region was lgkm-completed before the immediately
//     preceding barrier). Buf-switch reads (ph1/ph5 heads) stay after the
//     VMW(6)+BAR all-waves guarantee. VMW(6) counts re-derived: unchanged.
//     Dropped blanket lgkmcnt(0) (compiler emits counted waits). LDS reads
//     via 4 byte-base pointers so region+frag folds into offset immediates.

#define BK 64

typedef __bf16 bf16x8 __attribute__((ext_vector_type(8)));
typedef float  f32x4  __attribute__((ext_vector_type(4)));
typedef unsigned short u16x4 __attribute__((ext_vector_type(4)));

__device__ __forceinline__ unsigned short f2bf(float f) {
    unsigned int u = __builtin_bit_cast(unsigned int, f);
    u += 0x7fffu + ((u >> 16) & 1u);          // round-to-nearest-even
    return (unsigned short)(u >> 16);
}

__device__ __forceinline__ void async16(const void* g, void* l) {
    __builtin_amdgcn_global_load_lds(
        (const __attribute__((address_space(1))) unsigned int*)g,
        (__attribute__((address_space(3))) unsigned int*)l,
        16, 0, 0);
}

#define BAR()   __builtin_amdgcn_s_barrier()
#define VMW(n)  asm volatile("s_waitcnt vmcnt(" #n ")" ::: "memory")

// read 4 A rowfrags x 2 k-halves (8 x ds_read_b128), byte-region offsets
#define RDA(RBYTE) do { _Pragma("unroll") \
    for (int f = 0; f < 4; ++f) { \
        af[f][0] = *(const bf16x8*)(aB0 + (RBYTE) + f * 2048); \
        af[f][1] = *(const bf16x8*)(aB1 + (RBYTE) + f * 2048); } } while (0)

// read 2 B colfrags x 2 k-halves (4 x ds_read_b128)
#define RDB(DST, RBYTE) do { _Pragma("unroll") \
    for (int c = 0; c < 2; ++c) { \
        DST[c][0] = *(const bf16x8*)(bB0 + (RBYTE) + c * 2048); \
        DST[c][1] = *(const bf16x8*)(bB1 + (RBYTE) + c * 2048); } } while (0)

// 16 MFMA cluster (4 rowfrag x 2 colfrag x 2 k-halves), setprio-wrapped (T5)
#define MM16(HA, HB, AF, BF) do { \
    __builtin_amdgcn_s_setprio(1); \
    _Pragma("unroll") for (int f = 0; f < 4; ++f) \
    _Pragma("unroll") for (int c = 0; c < 2; ++c) { \
        acc[HA][f][HB][c] = __builtin_amdgcn_mfma_f32_16x16x32_bf16( \
            AF[f][0], BF[c][0], acc[HA][f][HB][c], 0, 0, 0); \
        acc[HA][f][HB][c] = __builtin_amdgcn_mfma_f32_16x16x32_bf16( \
            AF[f][1], BF[c][1], acc[HA][f][HB][c], 0, 0, 0); } \
    __builtin_amdgcn_s_setprio(0); } while (0)

// ---------------------------------------------------------------------------
// 8-phase 256x256 tile, BK=64, 512 threads. C = relu(A[M,K] * B[N,K]^T + b).
// LDS elem(row,c) at row*64 + (((c>>3) ^ (row&7))*8 + (c&7)) per 128x64 half.
// A halves at bytes 0/16K/32K/48K; B halves at 64K + 0/16K/32K/48K.
// ---------------------------------------------------------------------------
__global__ __launch_bounds__(512, 2)
void gemm8_bt_bias_relu(const unsigned short* __restrict__ A,
                        const unsigned short* __restrict__ B,
                        const float* __restrict__ bias,
                        unsigned short* __restrict__ C,
                        int M, int N, int K)
{
    __shared__ __align__(16) unsigned short L[65536];   // 128 KiB
    unsigned short* lds = L;

    // staging element offsets (A buf b half h = b*16384 + h*8192; B = +32768)
    constexpr int RA00 = 0,     RA01 = 8192,  RA10 = 16384, RA11 = 24576;
    constexpr int RB00 = 32768, RB01 = 40960, RB10 = 49152, RB11 = 57344;
    // fragment-read byte offsets (A area; B area is bB* base-relative)
    constexpr int A00b = 0, A01b = 16384, A10b = 32768, A11b = 49152;
    constexpr int B00b = 0, B01b = 16384, B10b = 32768, B11b = 49152;

    const int tid  = threadIdx.x;
    const int lane = tid & 63;
    const int wave = tid >> 6;
    const int quad = lane >> 4;
    const int l16  = lane & 15;
    const int wr   = wave >> 2;          // 0..1
    const int wc   = wave & 3;           // 0..3

    const int bm = blockIdx.x * 256;
    const int bn = blockIdx.y * 256;

    // ---- staging addressing (pre-swizzled global source, linear LDS dest)
    const int lrow = tid >> 3;                       // 0..63
    const int cswz = ((tid & 7) ^ (lrow & 7)) * 8;
    const int tid8 = tid * 8;
    const size_t rstep64 = (size_t)64 * K;
    const unsigned short* gaL = A + (size_t)(bm + lrow) * K + cswz;
    const unsigned short* gaH = gaL + (size_t)128 * K;
    const unsigned short* gbL = B + (size_t)(bn + lrow) * K + cswz;
    const unsigned short* gbH = gbL + (size_t)128 * K;

    auto stage = [&](const unsigned short* g, int region, int ko) {
        async16(g + ko,           lds + region + tid8);
        async16(g + rstep64 + ko, lds + region + 4096 + tid8);
    };

    // ---- fragment read base pointers (region+frag fold into imm offsets)
    const int xa = l16 & 7;
    const int c0 = (quad ^ xa) * 8;                  // k-half 0
    const int c1 = ((quad ^ 4) ^ xa) * 8;            // k-half 1
    const int aRd = (64 * wr + l16) * BK;
    const int bRd = (32 * wc + l16) * BK;
    const char* aB0 = (const char*)L + 2 * (aRd + c0);
    const char* aB1 = (const char*)L + 2 * (aRd + c1);
    const char* bB0 = (const char*)L + 65536 + 2 * (bRd + c0);
    const char* bB1 = (const char*)L + 65536 + 2 * (bRd + c1);

    f32x4 acc[2][4][2][2] = {};                      // [rowhalf][f][colhalf][c]
    bf16x8 af[4][2], bfl[2][2], bfh[2][2];

    // ---- prologue: tile0 all 4 halves -> buf0; tile1 A0,B0,B1 -> buf1
    stage(gaL, RA00, 0);
    stage(gbL, RB00, 0);
    stage(gbH, RB01, 0);
    stage(gaH, RA01, 0);
    stage(gaL, RA10, 64);
    stage(gbL, RB10, 64);
    stage(gbH, RB11, 64);
    VMW(6);                  // tile0 landed; tile1's 3 halves in flight
    BAR();                   // all waves' tile0 stages landed

    const int nIter = K >> 7;                        // 2 K-tiles per iter
    for (int i = 0; i < nIter; ++i) {
        const int k1 = (2 * i + 1) << 6;             // never exceeds K-64
        int k2 = (2 * i + 2) << 6; if (k2 >= K) k2 -= K;   // tail wrap
        int k3 = (2 * i + 3) << 6; if (k3 >= K) k3 -= K;

        // b1: buf-switch reads at head (post-BAR all-waves guarantee)
        RDA(A00b); RDB(bfl, B00b);
        MM16(0, 0, af, bfl);
        RDB(bfh, B01b);                  // reads for b2
        stage(gaH, RA11, k1);            // A1(t+1); RA11 read-done since b7'
        BAR();

        // b2
        MM16(0, 1, af, bfh);
        RDA(A01b);                       // reads for b3/b4 (A1 of t)
        stage(gaL, RA00, k2);            // A0(t+2); RA00 read-done < BAR(b1)
        BAR();

        // b3
        MM16(1, 1, af, bfh);
        stage(gbL, RB00, k2);            // B0(t+2)
        BAR();

        // b4 (pure-reg MFMA)
        MM16(1, 0, af, bfl);
        stage(gbH, RB01, k2);            // B1(t+2)
        VMW(6);                          // tile t+1 fully landed (all 4 halves)
        BAR();                           // ...for ALL waves

        // b5: buf-switch reads at head
        RDA(A10b); RDB(bfl, B10b);
        MM16(0, 0, af, bfl);
        RDB(bfh, B11b);                  // reads for b6
        stage(gaH, RA01, k2);            // A1(t+2); RA01 read-done < BAR(b3)
        BAR();

        // b6
        MM16(0, 1, af, bfh);
        RDA(A11b);                       // reads for b7/b8 (A1 of t+1)
        stage(gaL, RA10, k3);            // A0(t+3); RA10 read-done < BAR(b5)
        BAR();

        // b7
        MM16(1, 1, af, bfh);
        stage(gbL, RB10, k3);            // B0(t+3)
        BAR();

        // b8 (pure-reg MFMA)
        MM16(1, 0, af, bfl);
        stage(gbH, RB11, k3);            // B1(t+3)
        VMW(6);                          // tile t+2 fully landed
        BAR();
    }
    VMW(0);                  // drain wrapped stages before exit

    // ---- epilogue: bias + relu + bf16 store (R3 index algebra)
    float bv[2][2];
#pragma unroll
    for (int hb = 0; hb < 2; ++hb)
#pragma unroll
        for (int c = 0; c < 2; ++c)
            bv[hb][c] = bias[bn + hb * 128 + wc * 32 + c * 16 + l16];

#pragma unroll
    for (int ha = 0; ha < 2; ++ha)
#pragma unroll
    for (int f = 0; f < 4; ++f) {
        const int row0 = bm + ha * 128 + wr * 64 + f * 16 + quad * 4;
#pragma unroll
        for (int hb = 0; hb < 2; ++hb)
#pragma unroll
        for (int c = 0; c < 2; ++c) {
            const int col = bn + hb * 128 + wc * 32 + c * 16 + l16;
#pragma unroll
            for (int r = 0; r < 4; ++r) {
                float v = fmaxf(acc[ha][f][hb][c][r] + bv[hb][c], 0.0f);
                C[(size_t)(row0 + r) * N + col] = f2bf(v);
            }
        }
    }
}

// ---------------------------------------------------------------------------
// G4 + head fused: h4 = relu(A @ W4^T + b4) is NOT stored; each block
// computes partial dot(h4_row, Wo_cols) and atomicAdds into out[row].
// out pre-initialized to bo in prep_kernel. Block tile 128x128, acc[4][4].
// (unchanged -- ~20us, low-risk)
// ---------------------------------------------------------------------------
__global__ __launch_bounds__(256, 2)
void gemm_bt_head(const unsigned short* __restrict__ A,
                  const unsigned short* __restrict__ B,
                  const float* __restrict__ bias,
                  const float* __restrict__ Wo,
                  float* __restrict__ out,
                  int M, int N, int K)
{
    constexpr int BN = 128;
    constexpr int JT = 4;
    __shared__ __align__(16) unsigned short As[128 * BK];
    __shared__ __align__(16) unsigned short Bs[BN * BK];

    const int tid  = threadIdx.x;
    const int lane = tid & 63;
    const int wave = tid >> 6;
    const int quad = lane >> 4;
    const int l16  = lane & 15;

    const int bm = blockIdx.x * 128;
    const int bn = blockIdx.y * BN;
    const int wm = (wave & 1) * 64;
    const int wn = (wave >> 1) * 64;

    const int lrow = tid >> 3;
    const int gcol = ((tid & 7) ^ (lrow & 7)) * 8;

    const unsigned short* gaBase = A + (size_t)(bm + lrow) * K + gcol;
    const unsigned short* gbBase = B + (size_t)(bn + lrow) * K + gcol;

    unsigned short* lA = As + tid * 8;
    unsigned short* lB = Bs + tid * 8;

    const int xa = l16 & 7;
    const unsigned short* As_w = As + (wm + l16) * BK;
    const unsigned short* Bs_w = Bs + (wn + l16) * BK;
    const int c0 = (quad ^ xa) * 8;
    const int c1 = ((quad ^ 4) ^ xa) * 8;

    f32x4 acc[4][JT] = {};

    for (int k0 = 0; k0 < K; k0 += BK) {
#pragma unroll
        for (int i = 0; i < 4; ++i)
            async16(gaBase + (size_t)(i * 32) * K + k0, lA + i * 2048);
#pragma unroll
        for (int i = 0; i < JT; ++i)
            async16(gbBase + (size_t)(i * 32) * K + k0, lB + i * 2048);
        __syncthreads();

#pragma unroll
        for (int kk = 0; kk < 2; ++kk) {
            const int cs = kk ? c1 : c0;
            bf16x8 af[4], bfr[JT];
#pragma unroll
            for (int i = 0; i < 4; ++i)  af[i]  = *(const bf16x8*)(As_w + i * 16 * BK + cs);
#pragma unroll
            for (int j = 0; j < JT; ++j) bfr[j] = *(const bf16x8*)(Bs_w + j * 16 * BK + cs);
#pragma unroll
            for (int i = 0; i < 4; ++i)
#pragma unroll
                for (int j = 0; j < JT; ++j)
                    acc[i][j] = __builtin_amdgcn_mfma_f32_16x16x32_bf16(
                        af[i], bfr[j], acc[i][j], 0, 0, 0);
        }
        __syncthreads();
    }

    float bv[JT], wov[JT];
#pragma unroll
    for (int j = 0; j < JT; ++j) {
        const int col = bn + wn + j * 16 + l16;
        bv[j]  = bias[col];
        wov[j] = Wo[col];
    }

#pragma unroll
    for (int i = 0; i < 4; ++i) {
#pragma unroll
        for (int r = 0; r < 4; ++r) {
            float ws = 0.f;
#pragma unroll
            for (int j = 0; j < JT; ++j) {
                float v = acc[i][j][r] + bv[j];
                v = fmaxf(v, 0.0f);
                ws += v * wov[j];
            }
#pragma unroll
            for (int off = 8; off > 0; off >>= 1)
                ws += __shfl_xor(ws, off, 64);
            if (l16 == 0) {
                const int row = bm + wm + i * 16 + quad * 4 + r;
                atomicAdd(&out[row], ws);
            }
        }
    }
}

// ---------------------------------------------------------------------------
// Merged prep: [0,7680) convert W1..W4 fp32->bf16; [7680,11776) cross layer;
// [11776,11840) init out[m] = bo.   (unchanged)
// ---------------------------------------------------------------------------
__global__ __launch_bounds__(256)
void prep_kernel(const float* __restrict__ x, const float* __restrict__ cw,
                 const float* __restrict__ cb, unsigned short* __restrict__ h0,
                 const float* __restrict__ s1, const float* __restrict__ s2,
                 const float* __restrict__ s3, const float* __restrict__ s4,
                 unsigned short* __restrict__ d1, unsigned short* __restrict__ d2,
                 unsigned short* __restrict__ d3, unsigned short* __restrict__ d4,
                 const float* __restrict__ bo, float* __restrict__ out)
{
    const int b = blockIdx.x;
    if (b < 7680) {
        long t = (long)b * 256 + threadIdx.x;
        const float* s; unsigned short* d; long off;
        if (t < 262144L)       { s = s1; d = d1; off = t; }
        else if (t < 1310720L) { s = s2; d = d2; off = t - 262144L; }
        else if (t < 1835008L) { s = s3; d = d3; off = t - 1310720L; }
        else                   { s = s4; d = d4; off = t - 1835008L; }
        f32x4 f = *(const f32x4*)(s + off * 4);
        u16x4 o;
#pragma unroll
        for (int i = 0; i < 4; ++i) o[i] = f2bf(f[i]);
        *(u16x4*)(d + off * 4) = o;
    } else if (b < 11776) {
        const int row  = (b - 7680) * 4 + (threadIdx.x >> 6);
        const int lane = threadIdx.x & 63;
        const float* xr = x + (size_t)row * 512;
        float xv[8];
        float s = 0.f;
#pragma unroll
        for (int i = 0; i < 8; ++i) {
            const int c = lane + i * 64;
            xv[i] = xr[c];
            s += xv[i] * cw[c];
        }
#pragma unroll
        for (int off = 32; off > 0; off >>= 1) s += __shfl_down(s, off, 64);
        s = __shfl(s, 0, 64);
        unsigned short* hr = h0 + (size_t)row * 512;
#pragma unroll
        for (int i = 0; i < 8; ++i) {
            const int c = lane + i * 64;
            hr[c] = f2bf(xv[i] * s + cb[c] + xv[i]);
        }
    } else {
        const int t = (b - 11776) * 256 + threadIdx.x;   // 64 blocks = 16384
        out[t] = bo[0];
    }
}

// ---------------------------------------------------------------------------
extern "C" void kernel_launch(void* const* d_in, const int* in_sizes, int n_in,
                              void* d_out, int out_size, void* d_ws, size_t ws_size,
                              hipStream_t stream)
{
    const float* x  = (const float*)d_in[0];
    const float* cw = (const float*)d_in[1];
    const float* cb = (const float*)d_in[2];
    const float* W1 = (const float*)d_in[3];  const float* b1 = (const float*)d_in[4];
    const float* W2 = (const float*)d_in[5];  const float* b2 = (const float*)d_in[6];
    const float* W3 = (const float*)d_in[7];  const float* b3 = (const float*)d_in[8];
    const float* W4 = (const float*)d_in[9];  const float* b4 = (const float*)d_in[10];
    const float* Wo = (const float*)d_in[11]; const float* bo = (const float*)d_in[12];
    float* out = (float*)d_out;

    // workspace carve (~143 MB)
    char* p = (char*)d_ws;
    unsigned short* wb1 = (unsigned short*)p; p += (size_t)2048 * 512  * 2;
    unsigned short* wb2 = (unsigned short*)p; p += (size_t)2048 * 2048 * 2;
    unsigned short* wb3 = (unsigned short*)p; p += (size_t)1024 * 2048 * 2;
    unsigned short* wb4 = (unsigned short*)p; p += (size_t)512  * 1024 * 2;
    unsigned short* actA = (unsigned short*)p; p += (size_t)16384 * 2048 * 2; // h0,h2
    unsigned short* actB = (unsigned short*)p;                                // h1,h3

    prep_kernel<<<11840, 256, 0, stream>>>(x, cw, cb, actA,
                                           W1, W2, W3, W4, wb1, wb2, wb3, wb4,
                                           bo, out);

    // h1 = relu(h0 @ W1^T + b1)   [16384,2048], K=512
    gemm8_bt_bias_relu<<<dim3(64, 8), 512, 0, stream>>>(actA, wb1, b1, actB, 16384, 2048, 512);
    // h2 = relu(h1 @ W2^T + b2)   [16384,2048], K=2048
    gemm8_bt_bias_relu<<<dim3(64, 8), 512, 0, stream>>>(actB, wb2, b2, actA, 16384, 2048, 2048);
    // h3 = relu(h2 @ W3^T + b3)   [16384,1024], K=2048
    gemm8_bt_bias_relu<<<dim3(64, 4), 512, 0, stream>>>(actA, wb3, b3, actB, 16384, 1024, 2048);
    // out += sum_cols relu(h3 @ W4^T + b4) * Wo   [16384,512] fused head
    gemm_bt_head<<<dim3(128, 4), 256, 0, stream>>>(actB, wb4, b4, Wo, out, 16384, 512, 1024);
}

// Round 3
// 334.625 us; speedup vs baseline: 1.0729x; 1.0286x over previous
//
#include <hip/hip_runtime.h>

// Simple_Cross2: x[16384,512] -> cross -> 2048 -> 2048 -> 1024 -> 512 -> 1
// bf16 MFMA (16x16x32) GEMMs, fp32 accumulate, fused bias+relu.
// R2: BK=64 + XOR swizzle -> 0 bank conflicts.
// R3: 64x128 wave tile, block 128x256 2-phase -> G2 119us.
// R8: 8-phase 256x256 counted-vmcnt port -> G2 130us, MfmaUtil 44.7.
// R9: retimed (reads in prev phase tail, 1 barrier/phase) -> G2 124us,
//     MfmaUtil 48. Phase wall 1162cy vs 620cy MFMA floor (62% = m201).
// R10: the binding constraint was __launch_bounds__(512,2): 128 KiB LDS caps
//     at 1 block/CU anyway, so the 2-block request just halved the VGPR
//     budget to 128 -- acc alone needs 128, frags 64 more -> no headroom to
//     rename af/bfh across phases -> tail ds_reads serialize behind MFMA
//     issue (WAR). (512,1) -> 256 VGPR cap, frag double-buffering possible.

#define BK 64

typedef __bf16 bf16x8 __attribute__((ext_vector_type(8)));
typedef float  f32x4  __attribute__((ext_vector_type(4)));
typedef unsigned short u16x4 __attribute__((ext_vector_type(4)));

__device__ __forceinline__ unsigned short f2bf(float f) {
    unsigned int u = __builtin_bit_cast(unsigned int, f);
    u += 0x7fffu + ((u >> 16) & 1u);          // round-to-nearest-even
    return (unsigned short)(u >> 16);
}

__device__ __forceinline__ void async16(const void* g, void* l) {
    __builtin_amdgcn_global_load_lds(
        (const __attribute__((address_space(1))) unsigned int*)g,
        (__attribute__((address_space(3))) unsigned int*)l,
        16, 0, 0);
}

#define BAR()   __builtin_amdgcn_s_barrier()
#define VMW(n)  asm volatile("s_waitcnt vmcnt(" #n ")" ::: "memory")

// read 4 A rowfrags x 2 k-halves (8 x ds_read_b128), byte-region offsets
#define RDA(RBYTE) do { _Pragma("unroll") \
    for (int f = 0; f < 4; ++f) { \
        af[f][0] = *(const bf16x8*)(aB0 + (RBYTE) + f * 2048); \
        af[f][1] = *(const bf16x8*)(aB1 + (RBYTE) + f * 2048); } } while (0)

// read 2 B colfrags x 2 k-halves (4 x ds_read_b128)
#define RDB(DST, RBYTE) do { _Pragma("unroll") \
    for (int c = 0; c < 2; ++c) { \
        DST[c][0] = *(const bf16x8*)(bB0 + (RBYTE) + c * 2048); \
        DST[c][1] = *(const bf16x8*)(bB1 + (RBYTE) + c * 2048); } } while (0)

// 16 MFMA cluster (4 rowfrag x 2 colfrag x 2 k-halves), setprio-wrapped (T5)
#define MM16(HA, HB, AF, BF) do { \
    __builtin_amdgcn_s_setprio(1); \
    _Pragma("unroll") for (int f = 0; f < 4; ++f) \
    _Pragma("unroll") for (int c = 0; c < 2; ++c) { \
        acc[HA][f][HB][c] = __builtin_amdgcn_mfma_f32_16x16x32_bf16( \
            AF[f][0], BF[c][0], acc[HA][f][HB][c], 0, 0, 0); \
        acc[HA][f][HB][c] = __builtin_amdgcn_mfma_f32_16x16x32_bf16( \
            AF[f][1], BF[c][1], acc[HA][f][HB][c], 0, 0, 0); } \
    __builtin_amdgcn_s_setprio(0); } while (0)

// ---------------------------------------------------------------------------
// 8-phase 256x256 tile, BK=64, 512 threads. C = relu(A[M,K] * B[N,K]^T + b).
// LDS elem(row,c) at row*64 + (((c>>3) ^ (row&7))*8 + (c&7)) per 128x64 half.
// A halves at bytes 0/16K/32K/48K; B halves at 64K + 0/16K/32K/48K.
// ---------------------------------------------------------------------------
__global__ __launch_bounds__(512, 1)
void gemm8_bt_bias_relu(const unsigned short* __restrict__ A,
                        const unsigned short* __restrict__ B,
                        const float* __restrict__ bias,
                        unsigned short* __restrict__ C,
                        int M, int N, int K)
{
    __shared__ __align__(16) unsigned short L[65536];   // 128 KiB
    unsigned short* lds = L;

    // staging element offsets (A buf b half h = b*16384 + h*8192; B = +32768)
    constexpr int RA00 = 0,     RA01 = 8192,  RA10 = 16384, RA11 = 24576;
    constexpr int RB00 = 32768, RB01 = 40960, RB10 = 49152, RB11 = 57344;
    // fragment-read byte offsets
    constexpr int A00b = 0, A01b = 16384, A10b = 32768, A11b = 49152;
    constexpr int B00b = 0, B01b = 16384, B10b = 32768, B11b = 49152;

    const int tid  = threadIdx.x;
    const int lane = tid & 63;
    const int wave = tid >> 6;
    const int quad = lane >> 4;
    const int l16  = lane & 15;
    const int wr   = wave >> 2;          // 0..1
    const int wc   = wave & 3;           // 0..3

    const int bm = blockIdx.x * 256;
    const int bn = blockIdx.y * 256;

    // ---- staging addressing (pre-swizzled global source, linear LDS dest)
    const int lrow = tid >> 3;                       // 0..63
    const int cswz = ((tid & 7) ^ (lrow & 7)) * 8;
    const int tid8 = tid * 8;
    const size_t rstep64 = (size_t)64 * K;
    const unsigned short* gaL = A + (size_t)(bm + lrow) * K + cswz;
    const unsigned short* gaH = gaL + (size_t)128 * K;
    const unsigned short* gbL = B + (size_t)(bn + lrow) * K + cswz;
    const unsigned short* gbH = gbL + (size_t)128 * K;

    auto stage = [&](const unsigned short* g, int region, int ko) {
        async16(g + ko,           lds + region + tid8);
        async16(g + rstep64 + ko, lds + region + 4096 + tid8);
    };

    // ---- fragment read base pointers (region+frag fold into imm offsets)
    const int xa = l16 & 7;
    const int c0 = (quad ^ xa) * 8;                  // k-half 0
    const int c1 = ((quad ^ 4) ^ xa) * 8;            // k-half 1
    const int aRd = (64 * wr + l16) * BK;
    const int bRd = (32 * wc + l16) * BK;
    const char* aB0 = (const char*)L + 2 * (aRd + c0);
    const char* aB1 = (const char*)L + 2 * (aRd + c1);
    const char* bB0 = (const char*)L + 65536 + 2 * (bRd + c0);
    const char* bB1 = (const char*)L + 65536 + 2 * (bRd + c1);

    f32x4 acc[2][4][2][2] = {};                      // [rowhalf][f][colhalf][c]
    bf16x8 af[4][2], bfl[2][2], bfh[2][2];

    // ---- prologue: tile0 all 4 halves -> buf0; tile1 A0,B0,B1 -> buf1
    stage(gaL, RA00, 0);
    stage(gbL, RB00, 0);
    stage(gbH, RB01, 0);
    stage(gaH, RA01, 0);
    stage(gaL, RA10, 64);
    stage(gbL, RB10, 64);
    stage(gbH, RB11, 64);
    VMW(6);                  // tile0 landed; tile1's 3 halves in flight
    BAR();                   // all waves' tile0 stages landed

    const int nIter = K >> 7;                        // 2 K-tiles per iter
    for (int i = 0; i < nIter; ++i) {
        const int k1 = (2 * i + 1) << 6;             // never exceeds K-64
        int k2 = (2 * i + 2) << 6; if (k2 >= K) k2 -= K;   // tail wrap
        int k3 = (2 * i + 3) << 6; if (k3 >= K) k3 -= K;

        // b1: buf-switch reads at head (post-BAR all-waves guarantee)
        RDA(A00b); RDB(bfl, B00b);
        MM16(0, 0, af, bfl);
        RDB(bfh, B01b);                  // reads for b2
        stage(gaH, RA11, k1);            // A1(t+1); RA11 read-done since b7'
        BAR();

        // b2
        MM16(0, 1, af, bfh);
        RDA(A01b);                       // reads for b3/b4 (A1 of t)
        stage(gaL, RA00, k2);            // A0(t+2); RA00 read-done < BAR(b1)
        BAR();

        // b3
        MM16(1, 1, af, bfh);
        stage(gbL, RB00, k2);            // B0(t+2)
        BAR();

        // b4 (pure-reg MFMA)
        MM16(1, 0, af, bfl);
        stage(gbH, RB01, k2);            // B1(t+2)
        VMW(6);                          // tile t+1 fully landed (all 4 halves)
        BAR();                           // ...for ALL waves

        // b5: buf-switch reads at head
        RDA(A10b); RDB(bfl, B10b);
        MM16(0, 0, af, bfl);
        RDB(bfh, B11b);                  // reads for b6
        stage(gaH, RA01, k2);            // A1(t+2); RA01 read-done < BAR(b3)
        BAR();

        // b6
        MM16(0, 1, af, bfh);
        RDA(A11b);                       // reads for b7/b8 (A1 of t+1)
        stage(gaL, RA10, k3);            // A0(t+3); RA10 read-done < BAR(b5)
        BAR();

        // b7
        MM16(1, 1, af, bfh);
        stage(gbL, RB10, k3);            // B0(t+3)
        BAR();

        // b8 (pure-reg MFMA)
        MM16(1, 0, af, bfl);
        stage(gbH, RB11, k3);            // B1(t+3)
        VMW(6);                          // tile t+2 fully landed
        BAR();
    }
    VMW(0);                  // drain wrapped stages before exit

    // ---- epilogue: bias + relu + bf16 store (R3 index algebra)
    float bv[2][2];
#pragma unroll
    for (int hb = 0; hb < 2; ++hb)
#pragma unroll
        for (int c = 0; c < 2; ++c)
            bv[hb][c] = bias[bn + hb * 128 + wc * 32 + c * 16 + l16];

#pragma unroll
    for (int ha = 0; ha < 2; ++ha)
#pragma unroll
    for (int f = 0; f < 4; ++f) {
        const int row0 = bm + ha * 128 + wr * 64 + f * 16 + quad * 4;
#pragma unroll
        for (int hb = 0; hb < 2; ++hb)
#pragma unroll
        for (int c = 0; c < 2; ++c) {
            const int col = bn + hb * 128 + wc * 32 + c * 16 + l16;
#pragma unroll
            for (int r = 0; r < 4; ++r) {
                float v = fmaxf(acc[ha][f][hb][c][r] + bv[hb][c], 0.0f);
                C[(size_t)(row0 + r) * N + col] = f2bf(v);
            }
        }
    }
}

// ---------------------------------------------------------------------------
// G4 + head fused: h4 = relu(A @ W4^T + b4) is NOT stored; each block
// computes partial dot(h4_row, Wo_cols) and atomicAdds into out[row].
// out pre-initialized to bo in prep_kernel. Block tile 128x128, acc[4][4].
// (unchanged -- ~20us, low-risk)
// ---------------------------------------------------------------------------
__global__ __launch_bounds__(256, 2)
void gemm_bt_head(const unsigned short* __restrict__ A,
                  const unsigned short* __restrict__ B,
                  const float* __restrict__ bias,
                  const float* __restrict__ Wo,
                  float* __restrict__ out,
                  int M, int N, int K)
{
    constexpr int BN = 128;
    constexpr int JT = 4;
    __shared__ __align__(16) unsigned short As[128 * BK];
    __shared__ __align__(16) unsigned short Bs[BN * BK];

    const int tid  = threadIdx.x;
    const int lane = tid & 63;
    const int wave = tid >> 6;
    const int quad = lane >> 4;
    const int l16  = lane & 15;

    const int bm = blockIdx.x * 128;
    const int bn = blockIdx.y * BN;
    const int wm = (wave & 1) * 64;
    const int wn = (wave >> 1) * 64;

    const int lrow = tid >> 3;
    const int gcol = ((tid & 7) ^ (lrow & 7)) * 8;

    const unsigned short* gaBase = A + (size_t)(bm + lrow) * K + gcol;
    const unsigned short* gbBase = B + (size_t)(bn + lrow) * K + gcol;

    unsigned short* lA = As + tid * 8;
    unsigned short* lB = Bs + tid * 8;

    const int xa = l16 & 7;
    const unsigned short* As_w = As + (wm + l16) * BK;
    const unsigned short* Bs_w = Bs + (wn + l16) * BK;
    const int c0 = (quad ^ xa) * 8;
    const int c1 = ((quad ^ 4) ^ xa) * 8;

    f32x4 acc[4][JT] = {};

    for (int k0 = 0; k0 < K; k0 += BK) {
#pragma unroll
        for (int i = 0; i < 4; ++i)
            async16(gaBase + (size_t)(i * 32) * K + k0, lA + i * 2048);
#pragma unroll
        for (int i = 0; i < JT; ++i)
            async16(gbBase + (size_t)(i * 32) * K + k0, lB + i * 2048);
        __syncthreads();

#pragma unroll
        for (int kk = 0; kk < 2; ++kk) {
            const int cs = kk ? c1 : c0;
            bf16x8 af[4], bfr[JT];
#pragma unroll
            for (int i = 0; i < 4; ++i)  af[i]  = *(const bf16x8*)(As_w + i * 16 * BK + cs);
#pragma unroll
            for (int j = 0; j < JT; ++j) bfr[j] = *(const bf16x8*)(Bs_w + j * 16 * BK + cs);
#pragma unroll
            for (int i = 0; i < 4; ++i)
#pragma unroll
                for (int j = 0; j < JT; ++j)
                    acc[i][j] = __builtin_amdgcn_mfma_f32_16x16x32_bf16(
                        af[i], bfr[j], acc[i][j], 0, 0, 0);
        }
        __syncthreads();
    }

    float bv[JT], wov[JT];
#pragma unroll
    for (int j = 0; j < JT; ++j) {
        const int col = bn + wn + j * 16 + l16;
        bv[j]  = bias[col];
        wov[j] = Wo[col];
    }

#pragma unroll
    for (int i = 0; i < 4; ++i) {
#pragma unroll
        for (int r = 0; r < 4; ++r) {
            float ws = 0.f;
#pragma unroll
            for (int j = 0; j < JT; ++j) {
                float v = acc[i][j][r] + bv[j];
                v = fmaxf(v, 0.0f);
                ws += v * wov[j];
            }
#pragma unroll
            for (int off = 8; off > 0; off >>= 1)
                ws += __shfl_xor(ws, off, 64);
            if (l16 == 0) {
                const int row = bm + wm + i * 16 + quad * 4 + r;
                atomicAdd(&out[row], ws);
            }
        }
    }
}

// ---------------------------------------------------------------------------
// Merged prep: [0,7680) convert W1..W4 fp32->bf16; [7680,11776) cross layer;
// [11776,11840) init out[m] = bo.   (unchanged)
// ---------------------------------------------------------------------------
__global__ __launch_bounds__(256)
void prep_kernel(const float* __restrict__ x, const float* __restrict__ cw,
                 const float* __restrict__ cb, unsigned short* __restrict__ h0,
                 const float* __restrict__ s1, const float* __restrict__ s2,
                 const float* __restrict__ s3, const float* __restrict__ s4,
                 unsigned short* __restrict__ d1, unsigned short* __restrict__ d2,
                 unsigned short* __restrict__ d3, unsigned short* __restrict__ d4,
                 const float* __restrict__ bo, float* __restrict__ out)
{
    const int b = blockIdx.x;
    if (b < 7680) {
        long t = (long)b * 256 + threadIdx.x;
        const float* s; unsigned short* d; long off;
        if (t < 262144L)       { s = s1; d = d1; off = t; }
        else if (t < 1310720L) { s = s2; d = d2; off = t - 262144L; }
        else if (t < 1835008L) { s = s3; d = d3; off = t - 1310720L; }
        else                   { s = s4; d = d4; off = t - 1835008L; }
        f32x4 f = *(const f32x4*)(s + off * 4);
        u16x4 o;
#pragma unroll
        for (int i = 0; i < 4; ++i) o[i] = f2bf(f[i]);
        *(u16x4*)(d + off * 4) = o;
    } else if (b < 11776) {
        const int row  = (b - 7680) * 4 + (threadIdx.x >> 6);
        const int lane = threadIdx.x & 63;
        const float* xr = x + (size_t)row * 512;
        float xv[8];
        float s = 0.f;
#pragma unroll
        for (int i = 0; i < 8; ++i) {
            const int c = lane + i * 64;
            xv[i] = xr[c];
            s += xv[i] * cw[c];
        }
#pragma unroll
        for (int off = 32; off > 0; off >>= 1) s += __shfl_down(s, off, 64);
        s = __shfl(s, 0, 64);
        unsigned short* hr = h0 + (size_t)row * 512;
#pragma unroll
        for (int i = 0; i < 8; ++i) {
            const int c = lane + i * 64;
            hr[c] = f2bf(xv[i] * s + cb[c] + xv[i]);
        }
    } else {
        const int t = (b - 11776) * 256 + threadIdx.x;   // 64 blocks = 16384
        out[t] = bo[0];
    }
}

// ---------------------------------------------------------------------------
extern "C" void kernel_launch(void* const* d_in, const int* in_sizes, int n_in,
                              void* d_out, int out_size, void* d_ws, size_t ws_size,
                              hipStream_t stream)
{
    const float* x  = (const float*)d_in[0];
    const float* cw = (const float*)d_in[1];
    const float* cb = (const float*)d_in[2];
    const float* W1 = (const float*)d_in[3];  const float* b1 = (const float*)d_in[4];
    const float* W2 = (const float*)d_in[5];  const float* b2 = (const float*)d_in[6];
    const float* W3 = (const float*)d_in[7];  const float* b3 = (const float*)d_in[8];
    const float* W4 = (const float*)d_in[9];  const float* b4 = (const float*)d_in[10];
    const float* Wo = (const float*)d_in[11]; const float* bo = (const float*)d_in[12];
    float* out = (float*)d_out;

    // workspace carve (~143 MB)
    char* p = (char*)d_ws;
    unsigned short* wb1 = (unsigned short*)p; p += (size_t)2048 * 512  * 2;
    unsigned short* wb2 = (unsigned short*)p; p += (size_t)2048 * 2048 * 2;
    unsigned short* wb3 = (unsigned short*)p; p += (size_t)1024 * 2048 * 2;
    unsigned short* wb4 = (unsigned short*)p; p += (size_t)512  * 1024 * 2;
    unsigned short* actA = (unsigned short*)p; p += (size_t)16384 * 2048 * 2; // h0,h2
    unsigned short* actB = (unsigned short*)p;                                // h1,h3

    prep_kernel<<<11840, 256, 0, stream>>>(x, cw, cb, actA,
                                           W1, W2, W3, W4, wb1, wb2, wb3, wb4,
                                           bo, out);

    // h1 = relu(h0 @ W1^T + b1)   [16384,2048], K=512
    gemm8_bt_bias_relu<<<dim3(64, 8), 512, 0, stream>>>(actA, wb1, b1, actB, 16384, 2048, 512);
    // h2 = relu(h1 @ W2^T + b2)   [16384,2048], K=2048
    gemm8_bt_bias_relu<<<dim3(64, 8), 512, 0, stream>>>(actB, wb2, b2, actA, 16384, 2048, 2048);
    // h3 = relu(h2 @ W3^T + b3)   [16384,1024], K=2048
    gemm8_bt_bias_relu<<<dim3(64, 4), 512, 0, stream>>>(actA, wb3, b3, actB, 16384, 1024, 2048);
    // out += sum_cols relu(h3 @ W4^T + b4) * Wo   [16384,512] fused head
    gemm_bt_head<<<dim3(128, 4), 256, 0, stream>>>(actB, wb4, b4, Wo, out, 16384, 512, 1024);
}